// Round 4
// baseline (246.240 us; speedup 1.0000x reference)
//
#include <hip/hip_runtime.h>
#include <math.h>
#include <stdint.h>

#define Bn 8
#define Nn 2048
#define Cn 128
#define NKB (Nn / 32)   // 64 K-blocks of 32 columns each

typedef _Float16 f16x8 __attribute__((ext_vector_type(8)));
typedef _Float16 f16x2 __attribute__((ext_vector_type(2)));
typedef __fp16   fp16x2 __attribute__((ext_vector_type(2)));
typedef float    f32x4 __attribute__((ext_vector_type(4)));

// ---------------------------------------------------------------------------
// rows_kernel: fused prep + row transform. Per 64-row chunk of h:
//   v[c] = sum_d Ww[d][c]*aw[C+d]; b2 = Wb·aw2   (recomputed per block, L2/L3-hot)
//   wexp[b,n] = exp(h[b,n,:]·v + b2)
//   hTt[b][kb][c][ks] = (f16) h[b][kb*32+ks][c]  (K-blocked tiles; attn B-frag
//       loads are 1 KB contiguous). Stores packed f16x2 (4 B, 64 B segments).
// grid = 256 blocks (b = bid&7 for XCD-local L2 residency), 256 threads
// ---------------------------------------------------------------------------
__global__ __launch_bounds__(256) void rows_kernel(const float* __restrict__ h,
                                                   const float* __restrict__ Ww,
                                                   const float* __restrict__ Wb,
                                                   const float* __restrict__ aw,
                                                   float* __restrict__ wexp,
                                                   _Float16* __restrict__ hTt) {
    __shared__ float tile[64][132];
    __shared__ float vsh[128];
    __shared__ float vpart[128];
    __shared__ float b2sh;

    int bid = blockIdx.x;
    int b   = bid & 7;
    int n0  = (bid >> 3) << 6;
    int tid = threadIdx.x;

    // v partials: threads 0..127 do d in [0,64), 128..255 do d in [64,128)
    {
        int c = tid & 127, half = tid >> 7;
        float acc = 0.f;
#pragma unroll
        for (int dd = 0; dd < 64; ++dd) {
            int d = half * 64 + dd;
            acc += Ww[d * Cn + c] * aw[Cn + d];
        }
        if (half) vpart[c] = acc; else vsh[c] = acc;
    }
    if (tid < 64) {                      // b2 = Wb·aw2 by wave 0
        float b2p = Wb[tid] * aw[Cn + tid] + Wb[tid + 64] * aw[Cn + tid + 64];
        b2p += __shfl_xor(b2p, 32, 64);
        b2p += __shfl_xor(b2p, 16, 64);
        b2p += __shfl_xor(b2p, 8, 64);
        b2p += __shfl_xor(b2p, 4, 64);
        b2p += __shfl_xor(b2p, 2, 64);
        b2p += __shfl_xor(b2p, 1, 64);
        if (tid == 0) b2sh = b2p;
    }
    // stage 64x128 h tile, coalesced float4
    {
        int r = tid >> 2, qq = tid & 3;
        const float4* rowp = (const float4*)(h + (size_t)(b * Nn + n0 + r) * Cn);
#pragma unroll
        for (int i = 0; i < 8; ++i) {
            int f4 = i * 4 + qq;
            *(float4*)&tile[r][f4 * 4] = rowp[f4];
        }
    }
    __syncthreads();

    // dot h·v + exp: 4 threads per row, 32 elems each, shfl-combine
    {
        int r = tid >> 2, pp = tid & 3;
        float acc = 0.f;
#pragma unroll
        for (int ii = 0; ii < 32; ++ii) {
            int i = pp * 32 + ii;
            acc += tile[r][i] * (vsh[i] + vpart[i]);
        }
        acc += __shfl_xor(acc, 1, 64);
        acc += __shfl_xor(acc, 2, 64);
        if (pp == 0) wexp[b * Nn + n0 + r] = expf(acc + b2sh);
    }

    // packed f16x2 transposed stores: thread covers 2 adjacent ks, 16 c's
    {
        int kbl = (tid >> 4) & 1;            // which 32-k block of this 64-chunk
        int ks0 = (tid & 15) * 2;            // even ks
        int cg  = tid >> 5;                  // c group 0..7
        int kb  = (n0 >> 5) + kbl;
        int r0  = kbl * 32 + ks0;            // local rows r0, r0+1
        _Float16* base = hTt + ((size_t)(b * NKB + kb) * Cn) * 32 + ks0;
#pragma unroll
        for (int i = 0; i < 16; ++i) {
            int c = cg + 8 * i;
            f16x2 v2;
            v2[0] = (_Float16)tile[r0][c];
            v2[1] = (_Float16)tile[r0 + 1][c];
            *(f16x2*)(base + c * 32) = v2;
        }
    }
}

// ---------------------------------------------------------------------------
// attn_kernel: out[b,i,:] = (1/den_i) * sum_j (A[b,i,j]*w_j) * h[b,j,:]
// grid = 512 blocks (2/CU) x 512 threads (8 waves): 32 rows/block.
// waves: mt(2 row-tiles of 16) x ch(2 c-halves of 64) x kh(2 K-halves of 1024).
// Explicit ping-pong register double-buffer: iteration t+1's 6 global loads
// (4 hT B-frags + 2 A float4) issue before iteration t's MFMAs consume.
// ---------------------------------------------------------------------------
__global__ __launch_bounds__(512, 4) void attn_kernel(const float* __restrict__ A,
                                                      const float* __restrict__ wexp,
                                                      const _Float16* __restrict__ hTt,
                                                      float* __restrict__ out) {
    __shared__ float wLDS[Nn];           // 8 KB: w_j for this batch
    __shared__ float red[32][132];       // K-half-1 partial accumulators
    __shared__ float dred[32];           // K-half-1 partial denominators

    int bid = blockIdx.x;
    int b   = bid & 7;                   // XCD-aligned batch
    int i0  = (bid >> 3) << 5;
    int tid = threadIdx.x;
    int w = tid >> 6, l = tid & 63;
    int mt = w & 1, ch = (w >> 1) & 1, kh = w >> 2;
    int m = l & 15, q = l >> 4;
    int row_l = mt * 16 + m;

    const float*    Arow = A   + (size_t)(b * Nn + i0 + row_l) * Nn;
    const _Float16* hb   = hTt + (size_t)b * NKB * Cn * 32;

    // stage wexp into LDS (512 threads x float4 = 2048 floats)
    {
        const float4* ws4 = (const float4*)(wexp + (size_t)b * Nn);
        *(float4*)&wLDS[tid * 4] = ws4[tid];
    }
    __syncthreads();

    f32x4 acc[4];
#pragma unroll
    for (int cc = 0; cc < 4; ++cc) acc[cc] = (f32x4){0.f, 0.f, 0.f, 0.f};
    float dsum = 0.f;

    f16x8 bA[4], bB[4];
    float4 a0A, a1A, a0B, a1B;

    auto issue = [&](int t, f16x8* bf, float4& a0, float4& a1) {
        int kb = kh * 32 + t;
        const _Float16* hk = hb + (size_t)kb * (Cn * 32) + q * 8;
#pragma unroll
        for (int cc = 0; cc < 4; ++cc)
            bf[cc] = *(const f16x8*)(hk + ((ch * 4 + cc) * 16 + m) * 32);
        const float* ap = Arow + kb * 32 + q * 8;
        a0 = *(const float4*)ap;
        a1 = *(const float4*)(ap + 4);
    };
    auto compute = [&](int t, f16x8* bf, float4 a0, float4 a1) {
        int jq = (kh * 32 + t) * 32 + q * 8;
        float4 w0 = *(const float4*)&wLDS[jq];
        float4 w1 = *(const float4*)&wLDS[jq + 4];
        float p0 = a0.x * w0.x, p1 = a0.y * w0.y, p2 = a0.z * w0.z, p3 = a0.w * w0.w;
        float p4 = a1.x * w1.x, p5 = a1.y * w1.y, p6 = a1.z * w1.z, p7 = a1.w * w1.w;
        dsum += ((p0 + p1) + (p2 + p3)) + ((p4 + p5) + (p6 + p7));
        union { fp16x2 h2[4]; f16x8 v; } u;
        u.h2[0] = __builtin_amdgcn_cvt_pkrtz(p0, p1);
        u.h2[1] = __builtin_amdgcn_cvt_pkrtz(p2, p3);
        u.h2[2] = __builtin_amdgcn_cvt_pkrtz(p4, p5);
        u.h2[3] = __builtin_amdgcn_cvt_pkrtz(p6, p7);
#pragma unroll
        for (int cc = 0; cc < 4; ++cc)
            acc[cc] = __builtin_amdgcn_mfma_f32_16x16x32_f16(u.v, bf[cc], acc[cc], 0, 0, 0);
    };

    issue(0, bA, a0A, a1A);
    for (int t = 0; t < 32; t += 2) {
        issue((t + 1) & 31, bB, a0B, a1B);
        compute(t, bA, a0A, a1A);
        issue((t + 2) & 31, bA, a0A, a1A);   // t=30: wraps to 0, result discarded
        compute(t + 1, bB, a0B, a1B);
    }

    // denom: reduce across quads (lanes sharing m); all lanes end with row sum
    dsum += __shfl_xor(dsum, 16, 64);
    dsum += __shfl_xor(dsum, 32, 64);

    if (kh == 1) {                       // K-half 1 dumps partials
        if (ch == 0 && l < 16) dred[row_l] = dsum;
#pragma unroll
        for (int cc = 0; cc < 4; ++cc)
#pragma unroll
            for (int r = 0; r < 4; ++r)
                red[mt * 16 + q * 4 + r][(ch * 4 + cc) * 16 + m] = acc[cc][r];
    }
    __syncthreads();
    if (kh == 0) {                       // K-half 0 combines + normalizes + stores
        float dtot = dsum + dred[row_l];
        float invd = 1.f / dtot;         // lane l holds invd for row mt*16+(l&15)
        float* ob = out + (size_t)(b * Nn + i0 + mt * 16) * Cn;
#pragma unroll
        for (int r = 0; r < 4; ++r) {
            int rloc = q * 4 + r;        // C/D layout: row = q*4 + reg
            float iv = __shfl(invd, rloc, 64);
#pragma unroll
            for (int cc = 0; cc < 4; ++cc) {
                int c = (ch * 4 + cc) * 16 + m;
                float v = acc[cc][r] + red[mt * 16 + rloc][c];
                ob[(size_t)rloc * Cn + c] = v * iv;
            }
        }
    }
}

// ---------------------------------------------------------------------------
extern "C" void kernel_launch(void* const* d_in, const int* in_sizes, int n_in,
                              void* d_out, int out_size, void* d_ws, size_t ws_size,
                              hipStream_t stream) {
    const float* h  = (const float*)d_in[0];
    const float* A  = (const float*)d_in[1];
    const float* Ww = (const float*)d_in[2];
    const float* Wb = (const float*)d_in[3];
    const float* aw = (const float*)d_in[4];
    // d_in[5] = a_b : cancels in the row normalization, unused
    float* out = (float*)d_out;

    char* ws = (char*)d_ws;
    _Float16* hTt  = (_Float16*)ws;                                   // 4 MB
    float*    wexp = (float*)(ws + (size_t)Bn * NKB * Cn * 32 * 2);   // 64 KB

    rows_kernel<<<Bn * (Nn / 64), 256, 0, stream>>>(h, Ww, Wb, aw, wexp, hTt);
    attn_kernel<<<Bn * (Nn / 32), 512, 0, stream>>>(A, wexp, hTt, out);
}